// Round 4
// baseline (1147.261 us; speedup 1.0000x reference)
//
#include <hip/hip_runtime.h>

#define B_ 4
#define H_ 256
#define W_ 256
#define TSX 16
#define TSY 8
#define HALO 4
#define TWX (TSX + 2*HALO)   // 24
#define TWY (TSY + 2*HALO)   // 16
#define NPX (TWX * TWY)      // 384
#define PXF4 9               // float4 per pixel: 8 data + 1 pad (144 B stride, 16-B aligned)

// f32 dot of 32-register array vs one f32 LDS pixel row (8 x ds_read_b128, 4 accumulators)
__device__ __forceinline__ float dot32f(const float* a, const float4* r) {
    float s0 = 0.f, s1 = 0.f, s2 = 0.f, s3 = 0.f;
#pragma unroll
    for (int u = 0; u < 8; ++u) {
        float4 q = r[u];
        s0 += a[4*u+0] * q.x; s1 += a[4*u+1] * q.y;
        s2 += a[4*u+2] * q.z; s3 += a[4*u+3] * q.w;
    }
    return (s0 + s1) + (s2 + s3);
}

__global__ void __launch_bounds__(128)
gocor_main(const float* __restrict__ rf_g,
           const float* __restrict__ beta_p, const float* __restrict__ tw_p,
           const float* __restrict__ sw_p,  const float* __restrict__ mw_p,
           const float* __restrict__ mrw_p, const float* __restrict__ mrb_p,
           const float* __restrict__ lrw_p, const float* __restrict__ lrb_p,
           const float* __restrict__ wreg_p, const float* __restrict__ lsl_p,
           float* __restrict__ out)
{
    __shared__ float4 s_rf[NPX * PXF4];   // 55,296 B  (f32 tile, zero-padded halo)
    __shared__ float4 s_kp[81];           //  1,296 B  {A0, A1, Y, -}
    __shared__ float  s_mrb[32], s_lrb[32];

    const int tid = threadIdx.x;
    const int tx = tid & 15, ty = tid >> 4;            // 16 x 8 output pixels
    const int bx = blockIdx.x * TSX, by = blockIdx.y * TSY, bb = blockIdx.z;
    const float* rfb = rf_g + (size_t)bb * H_ * W_ * 32;

    // ---- stage f32 rf tile (+halo), zero outside image ----
    for (int idx = tid; idx < NPX * 8; idx += 128) {
        int u = idx & 7, p = idx >> 3;
        int ly = p / TWX, lx = p - ly * TWX;
        int gy = by + ly - HALO, gx = bx + lx - HALO;
        float4 v = make_float4(0.f, 0.f, 0.f, 0.f);
        if (gy >= 0 && gy < H_ && gx >= 0 && gx < W_)
            v = *(const float4*)(rfb + ((size_t)(gy * W_ + gx)) * 32 + u * 4);
        s_rf[p * PXF4 + u] = v;
    }

    // ---- per-block activation params (f32, faithful to reference) ----
    if (tid < 81) {
        int i = tid / 9, j = tid % 9;
        float di = (float)(i - 4), dj = (float)(j - 4);
        float dist = sqrtf(di * di + dj * dj);
        float y = 0.f, vp = 0.f, m = 0.f;
        for (int b = 0; b < 10; ++b) {
            float bd = 2.f * dist - (float)b;
            float val;
            if (i < 8) val = fmaxf(0.f, 1.f - fabsf(bd));        // triangular rows 0..7
            else       val = fminf(1.f, fmaxf(0.f, 1.f + bd));   // clipped row 8 (faithful)
            y  += val * tw_p[b];
            vp += val * sw_p[b];
            m  += val * mw_p[b];
        }
        float wm = 1.f / (1.f + expf(-m));
        s_kp[tid] = make_float4(vp * 0.5f * (1.f - wm),   // A0 = vp*(1-a)/2
                                vp * 0.5f * (1.f + wm),   // A1 = vp*(1+a)/2
                                vp * y, 0.f);             // Y  = vp*y
    }
    if (tid < 32)      s_mrb[tid]      = mrb_p[tid];
    else if (tid < 64) s_lrb[tid - 32] = lrb_p[tid - 32];

    float beta = beta_p[0];
    float wr   = wreg_p[0];
    float regw = fmaxf(wr * wr, (1e-5f * 1e-5f) / (32.f * 32.f));
    float step = expf(lsl_p[0]);

    __syncthreads();

    // ---- init: w = beta * rf / (mean(rf^2) + 1e-6) ----
    float w[32];
    {
        const float4* r = &s_rf[(((ty + HALO) * TWX) + (tx + HALO)) * PXF4];
#pragma unroll
        for (int u = 0; u < 8; ++u) {
            float4 q = r[u];
            w[4*u+0] = q.x; w[4*u+1] = q.y; w[4*u+2] = q.z; w[4*u+3] = q.w;
        }
        float msq = 0.f;
#pragma unroll
        for (int c = 0; c < 32; ++c) msq += w[c] * w[c];
        float inv = beta / (msq * (1.f / 32.f) + 1e-6f);
#pragma unroll
        for (int c = 0; c < 32; ++c) w[c] *= inv;
    }

    float mp[32], fg[32];

    for (int it = 0; it < 3; ++it) {
        // ---- Phase A: c_k -> s_k = dact*res; mapped = s @ mr_w + mr_b; record sign(c_k) ----
        unsigned long long sp0 = 0ull, sn0 = 0ull;   // k < 64
        unsigned int sp1 = 0u, sn1 = 0u;             // k >= 64
#pragma unroll
        for (int c = 0; c < 32; ++c) mp[c] = s_mrb[c];
        for (int i = 0; i < 9; ++i) {
            int rowbase = (ty + i) * TWX + tx;
            for (int j = 0; j < 9; ++j) {
                int k = i * 9 + j;
                const float4* r = &s_rf[(rowbase + j) * PXF4];
                float ck = dot32f(w, r) * (1.f / 32.f);
                if (ck > 0.f)      { if (k < 64) sp0 |= 1ull << k; else sp1 |= 1u << (k - 64); }
                else if (ck < 0.f) { if (k < 64) sn0 |= 1ull << k; else sn1 |= 1u << (k - 64); }
                float4 kp = s_kp[k];
                float sg = (ck > 0.f) ? 1.f : ((ck < 0.f) ? -1.f : 0.f);
                float act  = kp.x * fabsf(ck) + kp.y * ck;
                float res  = act - kp.z;
                float dact = kp.x * sg + kp.y;
                float s = dact * res;
                const float* mr = mrw_p + k * 32;    // wave-uniform -> s_load, K$-hot
#pragma unroll
                for (int c = 0; c < 32; ++c) mp[c] += s * mr[c];
            }
        }

        // ---- Phase B: filter_grad = regw*w + lcv(mapped, rf) @ lr_w + lr_b ----
#pragma unroll
        for (int c = 0; c < 32; ++c) fg[c] = s_lrb[c] + regw * w[c];
        for (int i = 0; i < 9; ++i) {
            int rowbase = (ty + i) * TWX + tx;
            for (int j = 0; j < 9; ++j) {
                int k = i * 9 + j;
                const float4* r = &s_rf[(rowbase + j) * PXF4];
                float ck = dot32f(mp, r) * (1.f / 32.f);
                const float* lr = lrw_p + k * 32;    // wave-uniform -> s_load
#pragma unroll
                for (int c = 0; c < 32; ++c) fg[c] += ck * lr[c];
            }
        }

        // ---- Phase C: alpha = sum(fg^2)/sum((dact*lcv(fg,rf))^2); w += alpha*step*fg ----
        float num = 0.f;
#pragma unroll
        for (int c = 0; c < 32; ++c) num += fg[c] * fg[c];
        float den = 0.f;
        for (int i = 0; i < 9; ++i) {
            int rowbase = (ty + i) * TWX + tx;
            for (int j = 0; j < 9; ++j) {
                int k = i * 9 + j;
                const float4* r = &s_rf[(rowbase + j) * PXF4];
                float c3 = dot32f(fg, r) * (1.f / 32.f);
                bool bp = (k < 64) ? ((sp0 >> k) & 1ull) : ((sp1 >> (k - 64)) & 1u);
                bool bn = (k < 64) ? ((sn0 >> k) & 1ull) : ((sn1 >> (k - 64)) & 1u);
                float sg = bp ? 1.f : (bn ? -1.f : 0.f);
                float4 kp = s_kp[k];
                float dact = kp.x * sg + kp.y;
                float s3 = dact * c3;
                den += s3 * s3;
            }
        }
        float as = (num / den) * step;
#pragma unroll
        for (int c = 0; c < 32; ++c) w[c] += as * fg[c];
    }

    // ---- f32 output, coalesced float4 stores ----
    float* o = out + (((size_t)bb * H_ + (by + ty)) * W_ + (bx + tx)) * 32;
#pragma unroll
    for (int u = 0; u < 8; ++u)
        *(float4*)(o + u * 4) = make_float4(w[4*u+0], w[4*u+1], w[4*u+2], w[4*u+3]);
}

extern "C" void kernel_launch(void* const* d_in, const int* in_sizes, int n_in,
                              void* d_out, int out_size, void* d_ws, size_t ws_size,
                              hipStream_t stream) {
    (void)d_ws; (void)ws_size; (void)in_sizes; (void)n_in; (void)out_size;
    dim3 grid(W_ / TSX, H_ / TSY, B_);
    hipLaunchKernelGGL(gocor_main, grid, dim3(128), 0, stream,
                       (const float*)d_in[0],   // reference_feature
                       (const float*)d_in[2],   // beta
                       (const float*)d_in[3],   // target_map_w
                       (const float*)d_in[4],   // spatial_w
                       (const float*)d_in[5],   // mask_w
                       (const float*)d_in[6],   // mr_w
                       (const float*)d_in[7],   // mr_b
                       (const float*)d_in[8],   // lr_w
                       (const float*)d_in[9],   // lr_b
                       (const float*)d_in[10],  // w_reg
                       (const float*)d_in[11],  // log_step_length
                       (float*)d_out);
}

// Round 5
// 678.223 us; speedup vs baseline: 1.6916x; 1.6916x over previous
//
#include <hip/hip_runtime.h>

#define B_ 4
#define H_ 256
#define W_ 256
#define PXF4 9   // float4 per pixel: 8 data + 1 pad (144 B stride, 16-B aligned)

// f32 dot of 32-register array vs one f32 LDS pixel row (8 x ds_read_b128, 4 accumulators)
// NOTE: numerics-load-bearing — do not change accumulation structure (absmax 12.625 verified).
__device__ __forceinline__ float dot32f(const float* a, const float4* r) {
    float s0 = 0.f, s1 = 0.f, s2 = 0.f, s3 = 0.f;
#pragma unroll
    for (int u = 0; u < 8; ++u) {
        float4 q = r[u];
        s0 += a[4*u+0] * q.x; s1 += a[4*u+1] * q.y;
        s2 += a[4*u+2] * q.z; s3 += a[4*u+3] * q.w;
    }
    return (s0 + s1) + (s2 + s3);
}

template<int TSX, int TSY, int NTH>
__global__ void __launch_bounds__(NTH)
gocor(const float* __restrict__ rf_g,
      const float* __restrict__ beta_p, const float* __restrict__ tw_p,
      const float* __restrict__ sw_p,  const float* __restrict__ mw_p,
      const float* __restrict__ mrw_p, const float* __restrict__ mrb_p,
      const float* __restrict__ lrw_p, const float* __restrict__ lrb_p,
      const float* __restrict__ wreg_p, const float* __restrict__ lsl_p,
      float* __restrict__ out)
{
    constexpr int TWXc = TSX + 8, TWYc = TSY + 8, NPXc = TWXc * TWYc;
    extern __shared__ float4 smem[];
    float4* s_rf  = smem;                    // NPXc * PXF4
    float4* s_kp  = smem + NPXc * PXF4;      // 81   {A0, A1, Y, -}
    float*  s_bias = (float*)(s_kp + 81);    // [0..32) mr_b, [32..64) lr_b

    const int tid = threadIdx.x;
    const int tx = tid % TSX, ty = tid / TSX;
    const int bx = blockIdx.x * TSX, by = blockIdx.y * TSY, bb = blockIdx.z;
    const float* rfb = rf_g + (size_t)bb * H_ * W_ * 32;

    // ---- stage f32 rf tile (+halo), zero outside image ----
    for (int idx = tid; idx < NPXc * 8; idx += NTH) {
        int u = idx & 7, p = idx >> 3;
        int ly = p / TWXc, lx = p - ly * TWXc;
        int gy = by + ly - 4, gx = bx + lx - 4;
        float4 v = make_float4(0.f, 0.f, 0.f, 0.f);
        if (gy >= 0 && gy < H_ && gx >= 0 && gx < W_)
            v = *(const float4*)(rfb + ((size_t)(gy * W_ + gx)) * 32 + u * 4);
        s_rf[p * PXF4 + u] = v;
    }

    // ---- per-block activation params (f32, faithful to reference) ----
    if (tid < 81) {
        int i = tid / 9, j = tid % 9;
        float di = (float)(i - 4), dj = (float)(j - 4);
        float dist = sqrtf(di * di + dj * dj);
        float y = 0.f, vp = 0.f, m = 0.f;
        for (int b = 0; b < 10; ++b) {
            float bd = 2.f * dist - (float)b;
            float val;
            if (i < 8) val = fmaxf(0.f, 1.f - fabsf(bd));        // triangular rows 0..7
            else       val = fminf(1.f, fmaxf(0.f, 1.f + bd));   // clipped row 8 (faithful)
            y  += val * tw_p[b];
            vp += val * sw_p[b];
            m  += val * mw_p[b];
        }
        float wm = 1.f / (1.f + expf(-m));
        s_kp[tid] = make_float4(vp * 0.5f * (1.f - wm),   // A0 = vp*(1-a)/2
                                vp * 0.5f * (1.f + wm),   // A1 = vp*(1+a)/2
                                vp * y, 0.f);             // Y  = vp*y
    }
    if (tid < 32)      s_bias[tid]      = mrb_p[tid];
    else if (tid < 64) s_bias[tid]      = lrb_p[tid - 32];

    float beta = beta_p[0];
    float wr   = wreg_p[0];
    float regw = fmaxf(wr * wr, (1e-5f * 1e-5f) / (32.f * 32.f));
    float step = expf(lsl_p[0]);

    __syncthreads();

    // ---- init: w = beta * rf / (mean(rf^2) + 1e-6) ----
    float w[32];
    {
        const float4* r = &s_rf[(((ty + 4) * TWXc) + (tx + 4)) * PXF4];
#pragma unroll
        for (int u = 0; u < 8; ++u) {
            float4 q = r[u];
            w[4*u+0] = q.x; w[4*u+1] = q.y; w[4*u+2] = q.z; w[4*u+3] = q.w;
        }
        float msq = 0.f;
#pragma unroll
        for (int c = 0; c < 32; ++c) msq += w[c] * w[c];
        float inv = beta / (msq * (1.f / 32.f) + 1e-6f);
#pragma unroll
        for (int c = 0; c < 32; ++c) w[c] *= inv;
    }

    float mp[32], fg[32];

    for (int it = 0; it < 3; ++it) {
        // ---- Phase A: c_k -> s = dact*res; mapped = s @ mr_w + mr_b; record sign(c_k) ----
        unsigned long long sp0 = 0ull, sn0 = 0ull;   // k < 64
        unsigned int sp1 = 0u, sn1 = 0u;             // k >= 64
#pragma unroll
        for (int c = 0; c < 32; ++c) mp[c] = s_bias[c];
        for (int i = 0; i < 9; ++i) {
            int rowbase = (ty + i) * TWXc + tx;
            for (int j = 0; j < 9; ++j) {
                int k = i * 9 + j;
                const float4* r = &s_rf[(rowbase + j) * PXF4];
                float ck = dot32f(w, r) * (1.f / 32.f);
                if (ck > 0.f)      { if (k < 64) sp0 |= 1ull << k; else sp1 |= 1u << (k - 64); }
                else if (ck < 0.f) { if (k < 64) sn0 |= 1ull << k; else sn1 |= 1u << (k - 64); }
                float4 kp = s_kp[k];
                float sg = (ck > 0.f) ? 1.f : ((ck < 0.f) ? -1.f : 0.f);
                float act  = kp.x * fabsf(ck) + kp.y * ck;
                float res  = act - kp.z;
                float dact = kp.x * sg + kp.y;
                float s = dact * res;
                const float* mr = mrw_p + k * 32;    // wave-uniform -> s_load, K$-hot
#pragma unroll
                for (int c = 0; c < 32; ++c) mp[c] += s * mr[c];
            }
        }

        // ---- Phase B: filter_grad = regw*w + lcv(mapped, rf) @ lr_w + lr_b ----
#pragma unroll
        for (int c = 0; c < 32; ++c) fg[c] = s_bias[32 + c] + regw * w[c];
        for (int i = 0; i < 9; ++i) {
            int rowbase = (ty + i) * TWXc + tx;
            for (int j = 0; j < 9; ++j) {
                int k = i * 9 + j;
                const float4* r = &s_rf[(rowbase + j) * PXF4];
                float ck = dot32f(mp, r) * (1.f / 32.f);
                const float* lr = lrw_p + k * 32;    // wave-uniform -> s_load
#pragma unroll
                for (int c = 0; c < 32; ++c) fg[c] += ck * lr[c];
            }
        }

        // ---- Phase C: alpha = sum(fg^2)/sum((dact*lcv(fg,rf))^2); w += alpha*step*fg ----
        float num = 0.f;
#pragma unroll
        for (int c = 0; c < 32; ++c) num += fg[c] * fg[c];
        float den = 0.f;
        for (int i = 0; i < 9; ++i) {
            int rowbase = (ty + i) * TWXc + tx;
            for (int j = 0; j < 9; ++j) {
                int k = i * 9 + j;
                const float4* r = &s_rf[(rowbase + j) * PXF4];
                float c3 = dot32f(fg, r) * (1.f / 32.f);
                bool bp = (k < 64) ? ((sp0 >> k) & 1ull) : ((sp1 >> (k - 64)) & 1u);
                bool bn = (k < 64) ? ((sn0 >> k) & 1ull) : ((sn1 >> (k - 64)) & 1u);
                float sg = bp ? 1.f : (bn ? -1.f : 0.f);
                float4 kp = s_kp[k];
                float dact = kp.x * sg + kp.y;
                float s3 = dact * c3;
                den += s3 * s3;
            }
        }
        float as = (num / den) * step;
#pragma unroll
        for (int c = 0; c < 32; ++c) w[c] += as * fg[c];
    }

    // ---- f32 output, coalesced float4 stores ----
    float* o = out + (((size_t)bb * H_ + (by + ty)) * W_ + (bx + tx)) * 32;
#pragma unroll
    for (int u = 0; u < 8; ++u)
        *(float4*)(o + u * 4) = make_float4(w[4*u+0], w[4*u+1], w[4*u+2], w[4*u+3]);
}

// ---- LDS sizes ----
// big:   32x16 tile -> 40x24 px -> (960*9 + 81 + 16) float4 = 139,792 B (1 block/CU, 8 waves)
// small: 16x8  tile -> 24x16 px -> (384*9 + 81 + 16) float4 =  56,848 B (2 blocks/CU, 4 waves)
static const size_t BIG_SHM   = (size_t)(40 * 24 * PXF4 + 81 + 16) * 16;
static const size_t SMALL_SHM = (size_t)(24 * 16 * PXF4 + 81 + 16) * 16;

static bool query_big_path() {
    // Runs once, on the first (uncaptured, correctness) call. No stream ops.
    int dev = 0;
    if (hipGetDevice(&dev) != hipSuccess) return false;
    // Opt-in for large dynamic LDS on the big instantiation (harmless if no-op).
    hipFuncSetAttribute(reinterpret_cast<const void*>(&gocor<32, 16, 512>),
                        hipFuncAttributeMaxDynamicSharedMemorySize, (int)BIG_SHM);
    int maxShm = 0;
    if (hipDeviceGetAttribute(&maxShm, hipDeviceAttributeMaxSharedMemoryPerBlock, dev) == hipSuccess &&
        (size_t)maxShm >= BIG_SHM)
        return true;
    hipFuncAttributes fa;
    if (hipFuncGetAttributes(&fa, reinterpret_cast<const void*>(&gocor<32, 16, 512>)) == hipSuccess &&
        (size_t)fa.maxDynamicSharedSizeBytes >= BIG_SHM)
        return true;
    return false;
}

extern "C" void kernel_launch(void* const* d_in, const int* in_sizes, int n_in,
                              void* d_out, int out_size, void* d_ws, size_t ws_size,
                              hipStream_t stream) {
    (void)d_ws; (void)ws_size; (void)in_sizes; (void)n_in; (void)out_size;
    static const bool use_big = query_big_path();   // resolved before graph capture

    const float* rf   = (const float*)d_in[0];
    const float* beta = (const float*)d_in[2];
    const float* tw   = (const float*)d_in[3];
    const float* sw   = (const float*)d_in[4];
    const float* mw   = (const float*)d_in[5];
    const float* mrw  = (const float*)d_in[6];
    const float* mrb  = (const float*)d_in[7];
    const float* lrw  = (const float*)d_in[8];
    const float* lrb  = (const float*)d_in[9];
    const float* wreg = (const float*)d_in[10];
    const float* lsl  = (const float*)d_in[11];
    float* o = (float*)d_out;

    if (use_big) {
        dim3 grid(W_ / 32, H_ / 16, B_);
        hipLaunchKernelGGL((gocor<32, 16, 512>), grid, dim3(512), BIG_SHM, stream,
                           rf, beta, tw, sw, mw, mrw, mrb, lrw, lrb, wreg, lsl, o);
    } else {
        dim3 grid(W_ / 16, H_ / 8, B_);
        hipLaunchKernelGGL((gocor<16, 8, 128>), grid, dim3(128), SMALL_SHM, stream,
                           rf, beta, tw, sw, mw, mrw, mrb, lrw, lrb, wreg, lsl, o);
    }
}